// Round 2
// baseline (1608.977 us; speedup 1.0000x reference)
//
#include <hip/hip_runtime.h>
#include <math.h>

// PairNetLayer fused implementation, round 2: all float tensors are FLOAT32
// (reference setup_inputs is jnp.float32; round-1 NaN was the signature of
// decoding f32 buffers as bf16). Structure: wave-per-row, per-wave LDS arena.
// Node kernel: na0 = o3_linear(node_attr, Wi*); h = o3_linear(norm_gate(node_attr, gp*), Wn*)
// Edge kernel: s0 -> fs/fe -> w -> TP -> norm_gate -> o3_linear -> +node_pair_attr

static __device__ __forceinline__ float siluf(float x) { return x / (1.f + __expf(-x)); }
static __device__ __forceinline__ float sspf(float x) {
  // softplus(x) - log(2), numerically stable
  return fmaxf(x, 0.f) + log1pf(__expf(-fabsf(x))) - 0.6931471805599453f;
}

// ---------------- node kernel: 1 wave per node, 4 nodes per block ----------------
__global__ __launch_bounds__(256) void node_kernel(
    const float* __restrict__ na,
    const float* __restrict__ Wi0, const float* __restrict__ bi0,
    const float* __restrict__ Wi1,
    const float* __restrict__ gpW1, const float* __restrict__ gpb1,
    const float* __restrict__ gpW2, const float* __restrict__ gpb2,
    const float* __restrict__ Wn0, const float* __restrict__ bn0,
    const float* __restrict__ Wn1,
    float* __restrict__ na0, float* __restrict__ h, int N)
{
  const int wave = threadIdx.x >> 6, lane = threadIdx.x & 63;
  int node = blockIdx.x * 4 + wave;
  const bool valid = node < N;
  if (node >= N) node = N - 1;
  __shared__ float lds[4][256 + 128 + 128 + 256];
  float* xrow = lds[wave];        // node_attr row
  float* f0   = xrow + 256;       // [s, nrm] 128
  float* t    = f0 + 128;         // silu hidden 128
  float* row2 = t + 128;          // norm_gate output row 256

  const float* xp = na + (size_t)node * 256;
  for (int i = lane; i < 256; i += 64) xrow[i] = xp[i];
  __syncthreads();

  // na0 = o3_linear(node_attr, Wi0, bi0, Wi1); lane = output channel v
  {
    const int v = lane;
    float sa = 0.f, a0 = 0.f, a1 = 0.f, a2 = 0.f;
#pragma unroll 4
    for (int u = 0; u < 64; ++u) {
      const float w0 = Wi0[u * 64 + v];
      const float w1 = Wi1[u * 64 + v];
      sa += xrow[u] * w0;
      a0 += xrow[64 + 3 * u + 0] * w1;
      a1 += xrow[64 + 3 * u + 1] * w1;
      a2 += xrow[64 + 3 * u + 2] * w1;
    }
    if (valid) {
      float* op = na0 + (size_t)node * 256;
      op[v] = sa * 0.125f + bi0[v];
      op[64 + 3 * v + 0] = a0 * 0.125f;
      op[64 + 3 * v + 1] = a1 * 0.125f;
      op[64 + 3 * v + 2] = a2 * 0.125f;
    }
  }

  // norm_gate(node_attr): build f0 = [s, |v|]
  {
    const int u = lane;
    const float v0 = xrow[64 + 3 * u], v1 = xrow[64 + 3 * u + 1], v2 = xrow[64 + 3 * u + 2];
    f0[u] = xrow[u];
    f0[64 + u] = sqrtf(v0 * v0 + v1 * v1 + v2 * v2);
  }
  __syncthreads();
  {
    float acc0 = gpb1[lane], acc1 = gpb1[64 + lane];
#pragma unroll 4
    for (int k = 0; k < 128; ++k) {
      const float fk = f0[k];
      acc0 += fk * gpW1[k * 128 + lane];
      acc1 += fk * gpW1[k * 128 + 64 + lane];
    }
    t[lane] = siluf(acc0);
    t[64 + lane] = siluf(acc1);
  }
  __syncthreads();
  {
    const int u = lane;
    float g0 = gpb2[u], g1 = gpb2[64 + u];
#pragma unroll 4
    for (int k = 0; k < 128; ++k) {
      const float tk = t[k];
      g0 += tk * gpW2[k * 128 + u];
      g1 += tk * gpW2[k * 128 + 64 + u];
    }
    row2[u] = g0;
    row2[64 + 3 * u + 0] = xrow[64 + 3 * u + 0] * g1;
    row2[64 + 3 * u + 1] = xrow[64 + 3 * u + 1] * g1;
    row2[64 + 3 * u + 2] = xrow[64 + 3 * u + 2] * g1;
  }
  __syncthreads();

  // h = o3_linear(row2, Wn0, bn0, Wn1)
  {
    const int v = lane;
    float sa = 0.f, a0 = 0.f, a1 = 0.f, a2 = 0.f;
#pragma unroll 4
    for (int u = 0; u < 64; ++u) {
      const float w0 = Wn0[u * 64 + v];
      const float w1 = Wn1[u * 64 + v];
      sa += row2[u] * w0;
      a0 += row2[64 + 3 * u + 0] * w1;
      a1 += row2[64 + 3 * u + 1] * w1;
      a2 += row2[64 + 3 * u + 2] * w1;
    }
    if (valid) {
      float* op = h + (size_t)node * 256;
      op[v] = sa * 0.125f + bn0[v];
      op[64 + 3 * v + 0] = a0 * 0.125f;
      op[64 + 3 * v + 1] = a1 * 0.125f;
      op[64 + 3 * v + 2] = a2 * 0.125f;
    }
  }
}

// ---------------- edge kernel: 1 wave per edge, 4 edges per block ----------------
__global__ __launch_bounds__(256) void edge_kernel(
    const float* __restrict__ ea,
    const float* __restrict__ npa,
    const float* __restrict__ feW1, const float* __restrict__ feW2,
    const float* __restrict__ fsW1, const float* __restrict__ fsb1,
    const float* __restrict__ fsW2, const float* __restrict__ fsb2,
    const float* __restrict__ gW1, const float* __restrict__ gb1,
    const float* __restrict__ gW2, const float* __restrict__ gb2,
    const float* __restrict__ Wo0, const float* __restrict__ bo0,
    const float* __restrict__ Wo1,
    const int* __restrict__ eidx,
    const float* __restrict__ na0, const float* __restrict__ h,
    float* __restrict__ out, int E)
{
  const int wave = threadIdx.x >> 6, lane = threadIdx.x & 63;
  int e = blockIdx.x * 4 + wave;
  const bool valid = e < E;
  if (e >= E) e = E - 1;
  // per-wave arena: s0 192 | hid2 64 | hid 16 | earow 32 | f0 128 | t 128 | row 256
  __shared__ float lds[4][192 + 64 + 16 + 32 + 128 + 128 + 256];
  float* s0    = lds[wave];
  float* hid2  = s0 + 192;
  float* hid   = hid2 + 64;
  float* earow = hid + 16;
  float* f0    = earow + 32;
  float* t     = f0 + 128;
  float* row   = t + 128;

  const int dst = eidx[e], src = eidx[E + e];
  const float* nad = na0 + (size_t)dst * 256;
  const float* nas = na0 + (size_t)src * 256;

  // s0 = [s_dst, s_src, ip/3]
  {
    const int u = lane;
    float ip = 0.f;
#pragma unroll
    for (int c = 0; c < 3; ++c) ip += nad[64 + 3 * u + c] * nas[64 + 3 * u + c];
    s0[u] = nad[u];
    s0[64 + u] = nas[u];
    s0[128 + u] = ip * (1.f / 3.f);
    if (lane < 32) earow[lane] = ea[(size_t)e * 32 + lane];
  }
  __syncthreads();

  // fs hidden (silu) and fe hidden (ssp)
  {
    float acc = fsb1[lane];
#pragma unroll 4
    for (int k = 0; k < 192; ++k) acc += s0[k] * fsW1[k * 64 + lane];
    hid2[lane] = siluf(acc);
    if (lane < 8) {
      float a = 0.f;
#pragma unroll 4
      for (int k = 0; k < 32; ++k) a += earow[k] * feW1[k * 8 + lane];
      hid[lane] = sspf(a * 0.17677669529663687f);  // 1/sqrt(32)
    }
  }
  __syncthreads();

  // w = fe * fs; lane u computes o = u + 64*i which is exactly its 5 TP weights
  float wreg[5];
#pragma unroll
  for (int i = 0; i < 5; ++i) {
    const int o = lane + 64 * i;
    float fe = 0.f;
#pragma unroll
    for (int j = 0; j < 8; ++j) fe += hid[j] * feW2[j * 320 + o];
    fe *= 0.35355339059327373f;  // 1/sqrt(8)
    float fsv = fsb2[o];
#pragma unroll 4
    for (int j = 0; j < 64; ++j) fsv += hid2[j] * fsW2[j * 320 + o];
    wreg[i] = fe * fsv;
  }

  // tensor product: x = h[src], y = h[dst]
  const float* hs = h + (size_t)src * 256;
  const float* hd = h + (size_t)dst * 256;
  {
    const int u = lane;
    const float xs = hs[u], ys = hd[u];
    const float xv0 = hs[64 + 3 * u], xv1 = hs[64 + 3 * u + 1], xv2 = hs[64 + 3 * u + 2];
    const float yv0 = hd[64 + 3 * u], yv1 = hd[64 + 3 * u + 1], yv2 = hd[64 + 3 * u + 2];
    const float ipv = xv0 * yv0 + xv1 * yv1 + xv2 * yv2;
    const float cr0 = xv1 * yv2 - xv2 * yv1;
    const float cr1 = xv2 * yv0 - xv0 * yv2;
    const float cr2 = xv0 * yv1 - xv1 * yv0;
    const float C0 = 0.4472135954999579f;   // sqrt(1/5)
    const float C1 = 0.7745966692414834f;   // sqrt(3/5)
    const float iS3 = 0.5773502691896258f;  // 1/sqrt(3)
    const float iS6 = 0.40824829046386307f; // 1/sqrt(6)
    const float ps = C0 * (wreg[0] * xs * ys + wreg[3] * ipv * iS3);
    const float k011 = C1 * iS3 * wreg[1] * xs;
    const float k101 = C1 * iS3 * wreg[2] * ys;
    const float k111 = C1 * iS6 * wreg[4];
    const float pv0 = k011 * yv0 + k101 * xv0 + k111 * cr0;
    const float pv1 = k011 * yv1 + k101 * xv1 + k111 * cr1;
    const float pv2 = k011 * yv2 + k101 * xv2 + k111 * cr2;
    row[u] = ps;
    row[64 + 3 * u + 0] = pv0;
    row[64 + 3 * u + 1] = pv1;
    row[64 + 3 * u + 2] = pv2;
    f0[u] = ps;
    f0[64 + u] = sqrtf(pv0 * pv0 + pv1 * pv1 + pv2 * pv2);
  }
  __syncthreads();

  // norm_gate on pair: hidden
  {
    float acc0 = gb1[lane], acc1 = gb1[64 + lane];
#pragma unroll 4
    for (int k = 0; k < 128; ++k) {
      const float fk = f0[k];
      acc0 += fk * gW1[k * 128 + lane];
      acc1 += fk * gW1[k * 128 + 64 + lane];
    }
    t[lane] = siluf(acc0);
    t[64 + lane] = siluf(acc1);
  }
  __syncthreads();
  {
    const int u = lane;
    float g0 = gb2[u], g1 = gb2[64 + u];
#pragma unroll 4
    for (int k = 0; k < 128; ++k) {
      const float tk = t[k];
      g0 += tk * gW2[k * 128 + u];
      g1 += tk * gW2[k * 128 + 64 + u];
    }
    row[u] = g0;                       // gated scalars
    row[64 + 3 * u + 0] *= g1;         // gate own vector elements in place
    row[64 + 3 * u + 1] *= g1;
    row[64 + 3 * u + 2] *= g1;
  }
  __syncthreads();

  // o3_linear(Wo) + residual
  {
    const int v = lane;
    float sa = 0.f, a0 = 0.f, a1 = 0.f, a2 = 0.f;
#pragma unroll 4
    for (int u = 0; u < 64; ++u) {
      const float w0 = Wo0[u * 64 + v];
      const float w1 = Wo1[u * 64 + v];
      sa += row[u] * w0;
      a0 += row[64 + 3 * u + 0] * w1;
      a1 += row[64 + 3 * u + 1] * w1;
      a2 += row[64 + 3 * u + 2] * w1;
    }
    if (valid) {
      const float* rp = npa + (size_t)e * 256;
      float* op = out + (size_t)e * 256;
      op[v] = sa * 0.125f + bo0[v] + rp[v];
      op[64 + 3 * v + 0] = a0 * 0.125f + rp[64 + 3 * v + 0];
      op[64 + 3 * v + 1] = a1 * 0.125f + rp[64 + 3 * v + 1];
      op[64 + 3 * v + 2] = a2 * 0.125f + rp[64 + 3 * v + 2];
    }
  }
}

extern "C" void kernel_launch(void* const* d_in, const int* in_sizes, int n_in,
                              void* d_out, int out_size, void* d_ws, size_t ws_size,
                              hipStream_t stream) {
  const float* node_attr = (const float*)d_in[0];
  const float* edge_attr = (const float*)d_in[1];
  const float* npa  = (const float*)d_in[2];
  const float* Wi0  = (const float*)d_in[3];
  const float* bi0  = (const float*)d_in[4];
  const float* Wi1  = (const float*)d_in[5];
  const float* gpW1 = (const float*)d_in[6];
  const float* gpb1 = (const float*)d_in[7];
  const float* gpW2 = (const float*)d_in[8];
  const float* gpb2 = (const float*)d_in[9];
  const float* Wn0  = (const float*)d_in[10];
  const float* bn0  = (const float*)d_in[11];
  const float* Wn1  = (const float*)d_in[12];
  const float* feW1 = (const float*)d_in[13];
  const float* feW2 = (const float*)d_in[14];
  const float* fsW1 = (const float*)d_in[15];
  const float* fsb1 = (const float*)d_in[16];
  const float* fsW2 = (const float*)d_in[17];
  const float* fsb2 = (const float*)d_in[18];
  const float* gW1  = (const float*)d_in[19];
  const float* gb1  = (const float*)d_in[20];
  const float* gW2  = (const float*)d_in[21];
  const float* gb2  = (const float*)d_in[22];
  const float* Wo0  = (const float*)d_in[23];
  const float* bo0  = (const float*)d_in[24];
  const float* Wo1  = (const float*)d_in[25];
  const int* eidx = (const int*)d_in[26];

  const int N = in_sizes[0] / 256;
  const int E = in_sizes[1] / 32;

  // workspace: na0 [N,256] f32, h [N,256] f32 (~41 MB)
  float* na0 = (float*)d_ws;
  float* h = na0 + (size_t)N * 256;

  node_kernel<<<(N + 3) / 4, 256, 0, stream>>>(node_attr, Wi0, bi0, Wi1, gpW1, gpb1,
                                               gpW2, gpb2, Wn0, bn0, Wn1, na0, h, N);
  edge_kernel<<<(E + 3) / 4, 256, 0, stream>>>(edge_attr, npa, feW1, feW2, fsW1, fsb1,
                                               fsW2, fsb2, gW1, gb1, gW2, gb2, Wo0, bo0,
                                               Wo1, eidx, na0, h, (float*)d_out, E);
}

// Round 4
// 995.593 us; speedup vs baseline: 1.6161x; 1.6161x over previous
//
#include <hip/hip_runtime.h>
#include <hip/hip_bf16.h>
#include <math.h>

// Round 4: same design as round 3 (edge pipeline as MFMA-batched GEMMs, 32 edges/block,
// bf16 weights/activations, f32 accumulate), with the `#pragma on code line` syntax
// error fixed via `f32x16 acc = {};` zero-init.

static __device__ __forceinline__ float siluf(float x) { return x / (1.f + __expf(-x)); }
static __device__ __forceinline__ float sspf(float x) {
  return fmaxf(x, 0.f) + log1pf(__expf(-fabsf(x))) - 0.6931471805599453f;
}
static __device__ __forceinline__ short f2b(float x) {
  __hip_bfloat16 b = __float2bfloat16(x);
  short s; __builtin_memcpy(&s, &b, 2); return s;
}
static __device__ __forceinline__ float b2f(short s) {
  unsigned int u = ((unsigned int)(unsigned short)s) << 16;
  float f; __builtin_memcpy(&f, &u, 4); return f;
}

typedef __attribute__((ext_vector_type(4))) short short4v;
typedef __attribute__((ext_vector_type(8))) short short8v;
typedef __attribute__((ext_vector_type(16))) float f32x16;

static __device__ __forceinline__ short8v ld8(const short* p) {
  // two ds_read_b64 (8B-aligned); strides chosen ≡ 4 mod 8 elems so this is legal
  const short4v* q = (const short4v*)p;
  short4v a = q[0], b = q[1];
  short8v r;
  r[0] = a[0]; r[1] = a[1]; r[2] = a[2]; r[3] = a[3];
  r[4] = b[0]; r[5] = b[1]; r[6] = b[2]; r[7] = b[3];
  return r;
}

// ---- ws bf16 weight layout (elem offsets), all [N][K_padded] transposed ----
// phase1: fsW1T [64][196] @0 | fsW2T [320][68] @12544 | feW1T [32][36] @34304 | feW2T [320][20] @35456  (total 41856)
// phase2: gW1T [128][132] @0 | gW2T [128][132] @16896 | Wo0T [64][68] @33792 | Wo1T [64][68] @38144   (total 42496)
#define P1_TOTAL 41856
#define P2_TOTAL 42496

__global__ __launch_bounds__(256) void prep_weights(
    const float* __restrict__ fsW1, const float* __restrict__ fsW2,
    const float* __restrict__ feW1, const float* __restrict__ feW2,
    const float* __restrict__ gW1, const float* __restrict__ gW2,
    const float* __restrict__ Wo0, const float* __restrict__ Wo1,
    short* __restrict__ wsb)
{
  const int gt = blockIdx.x * blockDim.x + threadIdx.x;
  const int gs = gridDim.x * blockDim.x;
  for (int i = gt; i < 64 * 196; i += gs) { int n = i / 196, k = i % 196; wsb[i] = (k < 192) ? f2b(fsW1[k * 64 + n]) : 0; }
  for (int i = gt; i < 320 * 68; i += gs) { int n = i / 68, k = i % 68; wsb[12544 + i] = (k < 64) ? f2b(fsW2[k * 320 + n]) : 0; }
  for (int i = gt; i < 32 * 36; i += gs) { int n = i / 36, k = i % 36; wsb[34304 + i] = (n < 8 && k < 32) ? f2b(feW1[k * 8 + n]) : 0; }
  for (int i = gt; i < 320 * 20; i += gs) { int n = i / 20, k = i % 20; wsb[35456 + i] = (k < 8) ? f2b(feW2[k * 320 + n]) : 0; }
  short* p2 = wsb + P1_TOTAL;
  for (int i = gt; i < 128 * 132; i += gs) { int n = i / 132, k = i % 132; p2[i] = (k < 128) ? f2b(gW1[k * 128 + n]) : 0; }
  for (int i = gt; i < 128 * 132; i += gs) { int n = i / 132, k = i % 132; p2[16896 + i] = (k < 128) ? f2b(gW2[k * 128 + n]) : 0; }
  for (int i = gt; i < 64 * 68; i += gs) { int n = i / 68, k = i % 68; p2[33792 + i] = (k < 64) ? f2b(Wo0[k * 64 + n]) : 0; }
  for (int i = gt; i < 64 * 68; i += gs) { int n = i / 68, k = i % 68; p2[38144 + i] = (k < 64) ? f2b(Wo1[k * 64 + n]) : 0; }
}

// ---------------- node kernel (unchanged from round 2) ----------------
__global__ __launch_bounds__(256) void node_kernel(
    const float* __restrict__ na,
    const float* __restrict__ Wi0, const float* __restrict__ bi0,
    const float* __restrict__ Wi1,
    const float* __restrict__ gpW1, const float* __restrict__ gpb1,
    const float* __restrict__ gpW2, const float* __restrict__ gpb2,
    const float* __restrict__ Wn0, const float* __restrict__ bn0,
    const float* __restrict__ Wn1,
    float* __restrict__ na0, float* __restrict__ h, int N)
{
  const int wave = threadIdx.x >> 6, lane = threadIdx.x & 63;
  int node = blockIdx.x * 4 + wave;
  const bool valid = node < N;
  if (node >= N) node = N - 1;
  __shared__ float lds[4][256 + 128 + 128 + 256];
  float* xrow = lds[wave];
  float* f0   = xrow + 256;
  float* t    = f0 + 128;
  float* row2 = t + 128;

  const float* xp = na + (size_t)node * 256;
  for (int i = lane; i < 256; i += 64) xrow[i] = xp[i];
  __syncthreads();
  {
    const int v = lane;
    float sa = 0.f, a0 = 0.f, a1 = 0.f, a2 = 0.f;
#pragma unroll 4
    for (int u = 0; u < 64; ++u) {
      const float w0 = Wi0[u * 64 + v];
      const float w1 = Wi1[u * 64 + v];
      sa += xrow[u] * w0;
      a0 += xrow[64 + 3 * u + 0] * w1;
      a1 += xrow[64 + 3 * u + 1] * w1;
      a2 += xrow[64 + 3 * u + 2] * w1;
    }
    if (valid) {
      float* op = na0 + (size_t)node * 256;
      op[v] = sa * 0.125f + bi0[v];
      op[64 + 3 * v + 0] = a0 * 0.125f;
      op[64 + 3 * v + 1] = a1 * 0.125f;
      op[64 + 3 * v + 2] = a2 * 0.125f;
    }
  }
  {
    const int u = lane;
    const float v0 = xrow[64 + 3 * u], v1 = xrow[64 + 3 * u + 1], v2 = xrow[64 + 3 * u + 2];
    f0[u] = xrow[u];
    f0[64 + u] = sqrtf(v0 * v0 + v1 * v1 + v2 * v2);
  }
  __syncthreads();
  {
    float acc0 = gpb1[lane], acc1 = gpb1[64 + lane];
#pragma unroll 4
    for (int k = 0; k < 128; ++k) {
      const float fk = f0[k];
      acc0 += fk * gpW1[k * 128 + lane];
      acc1 += fk * gpW1[k * 128 + 64 + lane];
    }
    t[lane] = siluf(acc0);
    t[64 + lane] = siluf(acc1);
  }
  __syncthreads();
  {
    const int u = lane;
    float g0 = gpb2[u], g1 = gpb2[64 + u];
#pragma unroll 4
    for (int k = 0; k < 128; ++k) {
      const float tk = t[k];
      g0 += tk * gpW2[k * 128 + u];
      g1 += tk * gpW2[k * 128 + 64 + u];
    }
    row2[u] = g0;
    row2[64 + 3 * u + 0] = xrow[64 + 3 * u + 0] * g1;
    row2[64 + 3 * u + 1] = xrow[64 + 3 * u + 1] * g1;
    row2[64 + 3 * u + 2] = xrow[64 + 3 * u + 2] * g1;
  }
  __syncthreads();
  {
    const int v = lane;
    float sa = 0.f, a0 = 0.f, a1 = 0.f, a2 = 0.f;
#pragma unroll 4
    for (int u = 0; u < 64; ++u) {
      const float w0 = Wn0[u * 64 + v];
      const float w1 = Wn1[u * 64 + v];
      sa += row2[u] * w0;
      a0 += row2[64 + 3 * u + 0] * w1;
      a1 += row2[64 + 3 * u + 1] * w1;
      a2 += row2[64 + 3 * u + 2] * w1;
    }
    if (valid) {
      float* op = h + (size_t)node * 256;
      op[v] = sa * 0.125f + bn0[v];
      op[64 + 3 * v + 0] = a0 * 0.125f;
      op[64 + 3 * v + 1] = a1 * 0.125f;
      op[64 + 3 * v + 2] = a2 * 0.125f;
    }
  }
}

// ---- LDS activation arena (shorts, offsets from act base) ----
// s0b [32][196]@0 | earowb [32][36]@6272 | hidEb [32][20]@7424 | hid2b [32][68]@8064
// wb [32][324]@10240 | f0b [32][132]@20608 | pvb [32][196]@24832 | tb [32][132]@31104  (total 35328)
// As = wb+0 [32][68]; Av_c = wb + 2176*(1+c) [32][68]
#define ACT_TOTAL 35328
#define LDS_SHORTS (P2_TOTAL + ACT_TOTAL)   // 77824 shorts = 155648 B

#define MFMA32(a, b, c) __builtin_amdgcn_mfma_f32_32x32x16_bf16(a, b, c, 0, 0, 0)

__global__ __launch_bounds__(256) void edge_kernel(
    const float* __restrict__ ea,
    const float* __restrict__ npa,
    const float* __restrict__ fsb1, const float* __restrict__ fsb2,
    const float* __restrict__ gb1, const float* __restrict__ gb2,
    const float* __restrict__ bo0,
    const int* __restrict__ eidx,
    const float* __restrict__ na0, const float* __restrict__ h,
    const short* __restrict__ wsb,
    float* __restrict__ out, int E)
{
  extern __shared__ __align__(16) short smem[];
  short* Wreg = smem;                 // weight region (both phases)
  short* act = smem + P2_TOTAL;
  short* s0b   = act;
  short* earowb = act + 6272;
  short* hidEb = act + 7424;
  short* hid2b = act + 8064;
  short* wb    = act + 10240;
  short* f0b   = act + 20608;
  short* pvb   = act + 24832;
  short* tb    = act + 31104;

  const int tid = threadIdx.x;
  const int wv = tid >> 6, ln = tid & 63;
  const int m32 = ln & 31, kh = ln >> 5;
  const int e0 = blockIdx.x * 32;

  const float C0c = 0.4472135954999579f;   // sqrt(1/5)
  const float C1c = 0.7745966692414834f;   // sqrt(3/5)
  const float iS3 = 0.5773502691896258f;
  const float iS6 = 0.40824829046386307f;
  const float isq32 = 0.17677669529663687f;
  const float isq8 = 0.35355339059327373f;

  // ---- phase-1 weight copy (ws -> LDS), 16B vectors ----
  {
    const uint4* src = (const uint4*)wsb;
    uint4* dst = (uint4*)Wreg;
    for (int i = tid; i < P1_TOTAL / 8; i += 256) dst[i] = src[i];
  }
  // ---- build: earow, hidE zero, s0 ----
  for (int i = tid; i < 32 * 32; i += 256) {
    int e = i >> 5, k = i & 31;
    int eg = e0 + e; if (eg >= E) eg = E - 1;
    earowb[e * 36 + k] = f2b(ea[(size_t)eg * 32 + k]);
  }
  for (int i = tid; i < 640; i += 256) hidEb[i] = 0;
  for (int i = 0; i < 8; ++i) {
    int e = wv * 8 + i;
    int eg = e0 + e; if (eg >= E) eg = E - 1;
    const int dst = eidx[eg], src = eidx[E + eg];
    const float* nd = na0 + (size_t)dst * 256;
    const float* ns = na0 + (size_t)src * 256;
    const int u = ln;
    float ip = nd[64 + 3 * u] * ns[64 + 3 * u] + nd[64 + 3 * u + 1] * ns[64 + 3 * u + 1]
             + nd[64 + 3 * u + 2] * ns[64 + 3 * u + 2];
    s0b[e * 196 + u] = f2b(nd[u]);
    s0b[e * 196 + 64 + u] = f2b(ns[u]);
    s0b[e * 196 + 128 + u] = f2b(ip * (1.f / 3.f));
  }
  __syncthreads();

  // ---- fs1: hid2 = silu(s0 @ fsW1 + fsb1)  [32,192]x[192,64], waves 0,1 ----
  if (wv < 2) {
    f32x16 acc = {};
    const int n = wv * 32 + m32;
    const short* A = s0b + m32 * 196 + kh * 8;
    const short* B = Wreg + n * 196 + kh * 8;
#pragma unroll
    for (int k0 = 0; k0 < 12; ++k0)
      acc = MFMA32(ld8(A + k0 * 16), ld8(B + k0 * 16), acc);
    const float bias = fsb1[n];
#pragma unroll
    for (int r = 0; r < 16; ++r) {
      int row = (r & 3) + 8 * (r >> 2) + 4 * kh;
      hid2b[row * 68 + n] = f2b(siluf(acc[r] + bias));
    }
  } else if (wv == 2) {
    // fe1: hidE = ssp((ea @ feW1) / sqrt(32))  [32,32]x[32,8]
    f32x16 acc = {};
    const short* A = earowb + m32 * 36 + kh * 8;
    const short* B = Wreg + 34304 + m32 * 36 + kh * 8;
#pragma unroll
    for (int k0 = 0; k0 < 2; ++k0)
      acc = MFMA32(ld8(A + k0 * 16), ld8(B + k0 * 16), acc);
    if (m32 < 8) {
#pragma unroll
      for (int r = 0; r < 16; ++r) {
        int row = (r & 3) + 8 * (r >> 2) + 4 * kh;
        hidEb[row * 20 + m32] = f2b(sspf(acc[r] * isq32));
      }
    }
  }
  __syncthreads();

  // ---- fe2: fe = (hidE @ feW2) / sqrt(8)  [32,8->16]x[8,320] -> wb ----
  for (int nt = wv; nt < 10; nt += 4) {
    f32x16 acc = {};
    const int n = nt * 32 + m32;
    acc = MFMA32(ld8(hidEb + m32 * 20 + kh * 8), ld8(Wreg + 35456 + n * 20 + kh * 8), acc);
#pragma unroll
    for (int r = 0; r < 16; ++r) {
      int row = (r & 3) + 8 * (r >> 2) + 4 * kh;
      wb[row * 324 + n] = f2b(acc[r] * isq8);
    }
  }
  __syncthreads();

  // ---- fs2: w = (hid2 @ fsW2 + fsb2) * fe  [32,64]x[64,320] -> wb in place ----
  for (int nt = wv; nt < 10; nt += 4) {
    f32x16 acc = {};
    const int n = nt * 32 + m32;
    const short* A = hid2b + m32 * 68 + kh * 8;
    const short* B = Wreg + 12544 + n * 68 + kh * 8;
#pragma unroll
    for (int k0 = 0; k0 < 4; ++k0)
      acc = MFMA32(ld8(A + k0 * 16), ld8(B + k0 * 16), acc);
    const float bias = fsb2[n];
#pragma unroll
    for (int r = 0; r < 16; ++r) {
      int row = (r & 3) + 8 * (r >> 2) + 4 * kh;
      float fsv = acc[r] + bias;
      wb[row * 324 + n] = f2b(fsv * b2f(wb[row * 324 + n]));
    }
  }
  __syncthreads();

  // ---- phase-2 weight copy (overwrites phase-1 region) ----
  {
    const uint4* src = (const uint4*)(wsb + P1_TOTAL);
    uint4* dst = (uint4*)Wreg;
    for (int i = tid; i < P2_TOTAL / 8; i += 256) dst[i] = src[i];
  }
  // ---- TP: pair = tp(h[src], h[dst], w) -> f0b (scalars+norms), pvb (vectors) ----
  for (int i = 0; i < 8; ++i) {
    int e = wv * 8 + i;
    int eg = e0 + e; if (eg >= E) eg = E - 1;
    const int dst = eidx[eg], src = eidx[E + eg];
    const float* hs = h + (size_t)src * 256;
    const float* hd = h + (size_t)dst * 256;
    const int u = ln;
    const float w0 = b2f(wb[e * 324 + u]);
    const float w1 = b2f(wb[e * 324 + u + 64]);
    const float w2 = b2f(wb[e * 324 + u + 128]);
    const float w3 = b2f(wb[e * 324 + u + 192]);
    const float w4 = b2f(wb[e * 324 + u + 256]);
    const float xs = hs[u], ys = hd[u];
    const float xv0 = hs[64 + 3 * u], xv1 = hs[64 + 3 * u + 1], xv2 = hs[64 + 3 * u + 2];
    const float yv0 = hd[64 + 3 * u], yv1 = hd[64 + 3 * u + 1], yv2 = hd[64 + 3 * u + 2];
    const float ipv = xv0 * yv0 + xv1 * yv1 + xv2 * yv2;
    const float cr0 = xv1 * yv2 - xv2 * yv1;
    const float cr1 = xv2 * yv0 - xv0 * yv2;
    const float cr2 = xv0 * yv1 - xv1 * yv0;
    const float ps = C0c * (w0 * xs * ys + w3 * ipv * iS3);
    const float k011 = C1c * iS3 * w1 * xs;
    const float k101 = C1c * iS3 * w2 * ys;
    const float k111 = C1c * iS6 * w4;
    const float pv0 = k011 * yv0 + k101 * xv0 + k111 * cr0;
    const float pv1 = k011 * yv1 + k101 * xv1 + k111 * cr1;
    const float pv2 = k011 * yv2 + k101 * xv2 + k111 * cr2;
    f0b[e * 132 + u] = f2b(ps);
    f0b[e * 132 + 64 + u] = f2b(sqrtf(pv0 * pv0 + pv1 * pv1 + pv2 * pv2));
    pvb[e * 196 + 3 * u + 0] = f2b(pv0);
    pvb[e * 196 + 3 * u + 1] = f2b(pv1);
    pvb[e * 196 + 3 * u + 2] = f2b(pv2);
  }
  __syncthreads();

  // ---- g1: t = silu(f0 @ gW1 + gb1)  [32,128]x[128,128] ----
  {
    f32x16 acc = {};
    const int n = wv * 32 + m32;
    const short* A = f0b + m32 * 132 + kh * 8;
    const short* B = Wreg + n * 132 + kh * 8;
#pragma unroll
    for (int k0 = 0; k0 < 8; ++k0)
      acc = MFMA32(ld8(A + k0 * 16), ld8(B + k0 * 16), acc);
    const float bias = gb1[n];
#pragma unroll
    for (int r = 0; r < 16; ++r) {
      int row = (r & 3) + 8 * (r >> 2) + 4 * kh;
      tb[row * 132 + n] = f2b(siluf(acc[r] + bias));
    }
  }
  __syncthreads();

  // ---- g2: g = t @ gW2 + gb2 ; gate -> As (scalar), Av_c (vector comps) in wb region ----
  {
    f32x16 acc = {};
    const int n = wv * 32 + m32;
    const short* A = tb + m32 * 132 + kh * 8;
    const short* B = Wreg + 16896 + n * 132 + kh * 8;
#pragma unroll
    for (int k0 = 0; k0 < 8; ++k0)
      acc = MFMA32(ld8(A + k0 * 16), ld8(B + k0 * 16), acc);
    const float bias = gb2[n];
#pragma unroll
    for (int r = 0; r < 16; ++r) {
      int row = (r & 3) + 8 * (r >> 2) + 4 * kh;
      float val = acc[r] + bias;
      if (wv < 2) {
        wb[row * 68 + n] = f2b(val);                    // As: gated scalars = g0
      } else {
        int u = n - 64;
        float p0 = b2f(pvb[row * 196 + 3 * u + 0]);
        float p1 = b2f(pvb[row * 196 + 3 * u + 1]);
        float p2 = b2f(pvb[row * 196 + 3 * u + 2]);
        wb[2176 * 1 + row * 68 + u] = f2b(p0 * val);
        wb[2176 * 2 + row * 68 + u] = f2b(p1 * val);
        wb[2176 * 3 + row * 68 + u] = f2b(p2 * val);
      }
    }
  }
  __syncthreads();

  // ---- Wo: out = o3_linear(gated, Wo0, bo0, Wo1) + npa ; wave wv owns comp wv ----
  {
    const short* A = wb + 2176 * wv + m32 * 68 + kh * 8;   // wv=0: As, else Av_{wv-1}
    const short* B0 = Wreg + (wv == 0 ? 33792 : 38144);
    for (int nt = 0; nt < 2; ++nt) {
      f32x16 acc = {};
      const int n = nt * 32 + m32;
      const short* B = B0 + n * 68 + kh * 8;
#pragma unroll
      for (int k0 = 0; k0 < 4; ++k0)
        acc = MFMA32(ld8(A + k0 * 16), ld8(B + k0 * 16), acc);
      const float bias = (wv == 0) ? bo0[n] : 0.f;
      const int off = (wv == 0) ? n : 64 + 3 * n + (wv - 1);
#pragma unroll
      for (int r = 0; r < 16; ++r) {
        int row = (r & 3) + 8 * (r >> 2) + 4 * kh;
        int eg = e0 + row;
        if (eg < E)
          out[(size_t)eg * 256 + off] = acc[r] * 0.125f + bias + npa[(size_t)eg * 256 + off];
      }
    }
  }
}

extern "C" void kernel_launch(void* const* d_in, const int* in_sizes, int n_in,
                              void* d_out, int out_size, void* d_ws, size_t ws_size,
                              hipStream_t stream) {
  const float* node_attr = (const float*)d_in[0];
  const float* edge_attr = (const float*)d_in[1];
  const float* npa  = (const float*)d_in[2];
  const float* Wi0  = (const float*)d_in[3];
  const float* bi0  = (const float*)d_in[4];
  const float* Wi1  = (const float*)d_in[5];
  const float* gpW1 = (const float*)d_in[6];
  const float* gpb1 = (const float*)d_in[7];
  const float* gpW2 = (const float*)d_in[8];
  const float* gpb2 = (const float*)d_in[9];
  const float* Wn0  = (const float*)d_in[10];
  const float* bn0  = (const float*)d_in[11];
  const float* Wn1  = (const float*)d_in[12];
  const float* feW1 = (const float*)d_in[13];
  const float* feW2 = (const float*)d_in[14];
  const float* fsW1 = (const float*)d_in[15];
  const float* fsb1 = (const float*)d_in[16];
  const float* fsW2 = (const float*)d_in[17];
  const float* fsb2 = (const float*)d_in[18];
  const float* gW1  = (const float*)d_in[19];
  const float* gb1  = (const float*)d_in[20];
  const float* gW2  = (const float*)d_in[21];
  const float* gb2  = (const float*)d_in[22];
  const float* Wo0  = (const float*)d_in[23];
  const float* bo0  = (const float*)d_in[24];
  const float* Wo1  = (const float*)d_in[25];
  const int* eidx = (const int*)d_in[26];

  const int N = in_sizes[0] / 256;
  const int E = in_sizes[1] / 32;

  float* na0 = (float*)d_ws;
  float* h = na0 + (size_t)N * 256;
  short* wsb = (short*)(h + (size_t)N * 256);   // bf16 transposed weights (~165 KB)

  (void)hipFuncSetAttribute((const void*)edge_kernel,
                            hipFuncAttributeMaxDynamicSharedMemorySize,
                            LDS_SHORTS * 2);

  prep_weights<<<96, 256, 0, stream>>>(fsW1, fsW2, feW1, feW2, gW1, gW2, Wo0, Wo1, wsb);
  node_kernel<<<(N + 3) / 4, 256, 0, stream>>>(node_attr, Wi0, bi0, Wi1, gpW1, gpb1,
                                               gpW2, gpb2, Wn0, bn0, Wn1, na0, h, N);
  edge_kernel<<<(E + 31) / 32, 256, LDS_SHORTS * 2, stream>>>(
      edge_attr, npa, fsb1, fsb2, gb1, gb2, bo0, eidx, na0, h, wsb, (float*)d_out, E);
}